// Round 2
// baseline (182.557 us; speedup 1.0000x reference)
//
#include <hip/hip_runtime.h>
#include <hip/hip_bf16.h>
#include <stdint.h>

// ECG beat tokenizer: X[196608, 64] = ecg_rows[196608, 128] @ W[64,128]^T + b
// plus beat_intervals[128*128] = 128.0f appended at out + 196608*64.
//
// Memory-bound skinny GEMM: ~151 MB mandatory traffic -> ~24us @ 6.3 TB/s.
// bf16 MFMA 16x16x32; A loaded global->reg in fragment layout (zero reuse),
// W (32KB, L2-resident) packed to registers per wave. One 16-row group per
// wave, 12288 waves total — no loop, pure TLP latency hiding.
// R1 fix: removed union type-punning (suspected alloca/scratch pathology);
// all fragment packing is SSA + __builtin_bit_cast.

#define BEAT_LEN   128
#define TOKEN_DIM  64
#define N_BATCH    128
#define N_BEATS    128
#define M_ROWS     196608          // 128*12*128 beat rows
#define RGROUPS    (M_ROWS / 16)   // 12288 row-groups of 16
#define WPB        4               // waves per block (256 threads)
#define NBLOCKS    (RGROUPS / WPB) // 3072 blocks -> exactly 1 row-group/wave

typedef __attribute__((ext_vector_type(4))) float    f32x4;
typedef __attribute__((ext_vector_type(8))) short    bf16x8;
typedef __attribute__((ext_vector_type(4))) uint32_t u32x4;

// pack two fp32 into one dword of 2x bf16 (round-half-up; error << threshold)
__device__ __forceinline__ uint32_t pkbf16(float a, float b) {
    uint32_t ua = __float_as_uint(a);
    uint32_t ub = __float_as_uint(b);
    return ((ua + 0x8000u) >> 16) | ((ub + 0x8000u) & 0xffff0000u);
}

__device__ __forceinline__ bf16x8 pack8(f32x4 lo, f32x4 hi) {
    u32x4 u;
    u.x = pkbf16(lo[0], lo[1]);
    u.y = pkbf16(lo[2], lo[3]);
    u.z = pkbf16(hi[0], hi[1]);
    u.w = pkbf16(hi[2], hi[3]);
    return __builtin_bit_cast(bf16x8, u);
}

__global__ __launch_bounds__(256) void ECGTokenizer_53420803228140_kernel(
    const float* __restrict__ ecg, const float* __restrict__ W,
    const float* __restrict__ b, float* __restrict__ out)
{
    const int lane = threadIdx.x & 63;
    const int wid  = threadIdx.x >> 6;
    const int l16  = lane & 15;   // A row / B col / D col within tile
    const int lg   = lane >> 4;   // k-chunk group (0..3)
    const int rg   = blockIdx.x * WPB + wid;   // 0..12287, exact

    // ---- A loads FIRST (HBM, long latency; hides under W load+pack) ----
    // Lane holds A[l16][32s + 8*lg + e], e=0..7 -> two contiguous float4.
    const float* arow = ecg + (size_t)rg * (16 * BEAT_LEN)
                      + (size_t)l16 * BEAT_LEN + 8 * lg;
    f32x4 a0[4], a1[4];
    #pragma unroll
    for (int s = 0; s < 4; ++s) {
        a0[s] = *(const f32x4*)(arow + 32*s);
        a1[s] = *(const f32x4*)(arow + 32*s + 4);
    }

    // ---- W fragments (L2-resident broadcast), packed incrementally ----
    // B[k][col] = W[col][k]; lane: col=16c+l16, k=32s+8*lg+e -> contiguous.
    bf16x8 wf[4][4]; // [coltile c][kstep s]
    #pragma unroll
    for (int c = 0; c < 4; ++c) {
        #pragma unroll
        for (int s = 0; s < 4; ++s) {
            const float* wp = W + (16*c + l16)*BEAT_LEN + 32*s + 8*lg;
            f32x4 w0 = *(const f32x4*)(wp);
            f32x4 w1 = *(const f32x4*)(wp + 4);
            wf[c][s] = pack8(w0, w1);
        }
    }
    float bv[4];
    #pragma unroll
    for (int c = 0; c < 4; ++c) bv[c] = b[16*c + l16];

    f32x4 acc[4];
    #pragma unroll
    for (int c = 0; c < 4; ++c) acc[c] = (f32x4){bv[c], bv[c], bv[c], bv[c]};

    #pragma unroll
    for (int s = 0; s < 4; ++s) {
        bf16x8 af = pack8(a0[s], a1[s]);
        #pragma unroll
        for (int c = 0; c < 4; ++c)
            acc[c] = __builtin_amdgcn_mfma_f32_16x16x32_bf16(
                         af, wf[c][s], acc[c], 0, 0, 0);
    }

    // D mapping (verified m89/m91): col = lane&15, row = 4*(lane>>4)+reg
    float* orow = out + (size_t)rg * (16 * TOKEN_DIM);
    #pragma unroll
    for (int c = 0; c < 4; ++c) {
        #pragma unroll
        for (int r = 0; r < 4; ++r) {
            orow[(4*lg + r) * TOKEN_DIM + 16*c + l16] = acc[c][r];
        }
    }

    // beat_intervals [128,128] = 128.0f, appended after X
    const int gtid = blockIdx.x * blockDim.x + threadIdx.x;
    if (gtid < N_BATCH * N_BEATS) {
        out[(size_t)M_ROWS * TOKEN_DIM + gtid] = 128.0f;
    }
}

extern "C" void kernel_launch(void* const* d_in, const int* in_sizes, int n_in,
                              void* d_out, int out_size, void* d_ws, size_t ws_size,
                              hipStream_t stream) {
    const float* ecg = (const float*)d_in[0];
    const float* W   = (const float*)d_in[1];
    const float* b   = (const float*)d_in[2];
    float* out       = (float*)d_out;
    hipLaunchKernelGGL(ECGTokenizer_53420803228140_kernel,
                       dim3(NBLOCKS), dim3(256), 0, stream,
                       ecg, W, b, out);
}

// Round 3
// 167.476 us; speedup vs baseline: 1.0900x; 1.0900x over previous
//
#include <hip/hip_runtime.h>
#include <hip/hip_bf16.h>
#include <stdint.h>

// ECG beat tokenizer: X[196608, 64] = ecg_rows[196608, 128] @ W[64,128]^T + b
// plus beat_intervals[128*128] = 128.0f appended at out + 196608*64.
//
// Memory-bound skinny GEMM (~150 MB traffic -> ~24us @6.3TB/s floor).
// R3 design:
//  - swapped mfma operands: D = mfma(W_frag, ecg_frag) => lane's 4 acc regs
//    are 4 consecutive token_dim entries -> dwordx4 stores (4 instrs vs 16)
//  - 768 blocks x 4 waves = 3072 waves (3 blocks/CU, fully co-resident),
//    4 row-groups per wave => W load+pack amortized 4x
//  - software prefetch of next row-group's A ahead of MFMA+stores

#define BEAT_LEN   128
#define TOKEN_DIM  64
#define N_BATCH    128
#define N_BEATS    128
#define M_ROWS     196608          // 128*12*128 beat rows
#define RGROUPS    (M_ROWS / 16)   // 12288 row-groups of 16
#define WPB        4               // waves per block (256 threads)
#define NBLOCKS    768             // 3 blocks/CU, grid fully co-resident
#define NWAVES     (NBLOCKS * WPB) // 3072
#define ITERS      (RGROUPS / NWAVES) // 4 row-groups per wave

typedef __attribute__((ext_vector_type(4))) float    f32x4;
typedef __attribute__((ext_vector_type(8))) short    bf16x8;
typedef __attribute__((ext_vector_type(4))) uint32_t u32x4;

// pack two fp32 into one dword of 2x bf16 (round-half-up)
__device__ __forceinline__ uint32_t pkbf16(float a, float b) {
    uint32_t ua = __float_as_uint(a);
    uint32_t ub = __float_as_uint(b);
    return ((ua + 0x8000u) >> 16) | ((ub + 0x8000u) & 0xffff0000u);
}

__device__ __forceinline__ bf16x8 pack8(f32x4 lo, f32x4 hi) {
    u32x4 u;
    u.x = pkbf16(lo[0], lo[1]);
    u.y = pkbf16(lo[2], lo[3]);
    u.z = pkbf16(hi[0], hi[1]);
    u.w = pkbf16(hi[2], hi[3]);
    return __builtin_bit_cast(bf16x8, u);
}

__global__ __launch_bounds__(256, 3) void ECGTokenizer_53420803228140_kernel(
    const float* __restrict__ ecg, const float* __restrict__ W,
    const float* __restrict__ b, float* __restrict__ out)
{
    const int lane = threadIdx.x & 63;
    const int wid  = threadIdx.x >> 6;
    const int l16  = lane & 15;   // fragment index (W row d / ecg row m)
    const int lg   = lane >> 4;   // k-subgroup (0..3)
    const int gwave = blockIdx.x * WPB + wid;  // 0..3071
    int rg = gwave * ITERS;                    // 4 consecutive row-groups

    // ---- first A row-group loads issued immediately (HBM) ----
    // Lane holds ecg[rg*16 + l16][32s + 8*lg + e], e=0..7
    const float* arow = ecg + (size_t)rg * (16 * BEAT_LEN)
                      + (size_t)l16 * BEAT_LEN + 8 * lg;
    f32x4 a0[4], a1[4];
    #pragma unroll
    for (int s = 0; s < 4; ++s) {
        a0[s] = *(const f32x4*)(arow + 32*s);
        a1[s] = *(const f32x4*)(arow + 32*s + 4);
    }

    // ---- W fragments (A-operand side), held all kernel ----
    // lane holds W[16c + l16][32s + 8*lg + e] -> contiguous 8 fp32
    bf16x8 wf[4][4]; // [dtile c][kstep s]
    #pragma unroll
    for (int c = 0; c < 4; ++c) {
        #pragma unroll
        for (int s = 0; s < 4; ++s) {
            const float* wp = W + (16*c + l16)*BEAT_LEN + 32*s + 8*lg;
            f32x4 w0 = *(const f32x4*)(wp);
            f32x4 w1 = *(const f32x4*)(wp + 4);
            wf[c][s] = pack8(w0, w1);
        }
    }
    // bias: lane's 4 acc entries are d = 16c + 4*lg + {0..3} -> contiguous
    f32x4 bvv[4];
    #pragma unroll
    for (int c = 0; c < 4; ++c) bvv[c] = *(const f32x4*)(b + 16*c + 4*lg);

    #pragma unroll
    for (int it = 0; it < ITERS; ++it) {
        // pack current A (waits on its loads)
        bf16x8 af[4];
        #pragma unroll
        for (int s = 0; s < 4; ++s) af[s] = pack8(a0[s], a1[s]);

        // prefetch next row-group BEFORE mfma/stores (loads ahead of stores
        // in the vmcnt queue; latency hides under compute of this iter)
        if (it + 1 < ITERS) {
            const float* anext = ecg + (size_t)(rg + 1) * (16 * BEAT_LEN)
                               + (size_t)l16 * BEAT_LEN + 8 * lg;
            #pragma unroll
            for (int s = 0; s < 4; ++s) {
                a0[s] = *(const f32x4*)(anext + 32*s);
                a1[s] = *(const f32x4*)(anext + 32*s + 4);
            }
        }

        f32x4 acc[4];
        #pragma unroll
        for (int c = 0; c < 4; ++c) acc[c] = bvv[c];

        #pragma unroll
        for (int s = 0; s < 4; ++s) {
            #pragma unroll
            for (int c = 0; c < 4; ++c)
                acc[c] = __builtin_amdgcn_mfma_f32_16x16x32_bf16(
                             wf[c][s], af[s], acc[c], 0, 0, 0);
        }

        // D: row (W dim) = 4*lg + reg, col (m dim) = l16
        // lane stores X[rg*16 + l16][16c + 4lg .. +3] -> one dwordx4 per c
        float* orow = out + ((size_t)rg * 16 + l16) * TOKEN_DIM + 4*lg;
        #pragma unroll
        for (int c = 0; c < 4; ++c) {
            *(f32x4*)(orow + 16*c) = acc[c];
        }
        ++rg;
    }

    // beat_intervals [128,128] = 128.0f, appended after X
    const int gtid = blockIdx.x * blockDim.x + threadIdx.x;
    if (gtid < N_BATCH * N_BEATS) {
        out[(size_t)M_ROWS * TOKEN_DIM + gtid] = 128.0f;
    }
}

extern "C" void kernel_launch(void* const* d_in, const int* in_sizes, int n_in,
                              void* d_out, int out_size, void* d_ws, size_t ws_size,
                              hipStream_t stream) {
    const float* ecg = (const float*)d_in[0];
    const float* W   = (const float*)d_in[1];
    const float* b   = (const float*)d_in[2];
    float* out       = (float*)d_out;
    hipLaunchKernelGGL(ECGTokenizer_53420803228140_kernel,
                       dim3(NBLOCKS), dim3(256), 0, stream,
                       ecg, W, b, out);
}

// Round 4
// 167.119 us; speedup vs baseline: 1.0924x; 1.0021x over previous
//
#include <hip/hip_runtime.h>
#include <hip/hip_bf16.h>
#include <stdint.h>

// ECG beat tokenizer: X[196608, 64] = ecg_rows[196608, 128] @ W[64,128]^T + b
// plus beat_intervals[128*128] = 128.0f appended at out + 196608*64.
//
// Memory-bound skinny GEMM (~150 MB traffic -> ~24us @6.3TB/s floor).
// R4: W staged to LDS in MFMA-fragment order (conflict-free contiguous
// ds_read_b128 per fragment) -> per-wave VGPR demand ~80, no spills
// (R2 showed VGPR=68 vs ~130 needed => scratch serialization was the
// latency pathology). 1024 blocks x 4 waves, 4 blocks/CU co-resident,
// 3 row-groups/wave with A prefetch. Nontemporal output stores.

#define BEAT_LEN   128
#define TOKEN_DIM  64
#define N_BATCH    128
#define N_BEATS    128
#define M_ROWS     196608          // 128*12*128 beat rows
#define RGROUPS    (M_ROWS / 16)   // 12288 row-groups of 16
#define WPB        4               // waves per block (256 threads)
#define NBLOCKS    1024            // 4 blocks/CU, grid co-resident
#define NWAVES     (NBLOCKS * WPB) // 4096
#define ITERS      (RGROUPS / NWAVES) // 3 row-groups per wave

typedef __attribute__((ext_vector_type(4))) float    f32x4;
typedef __attribute__((ext_vector_type(8))) short    bf16x8;
typedef __attribute__((ext_vector_type(4))) uint32_t u32x4;

// pack two fp32 into one dword of 2x bf16 (round-half-up)
__device__ __forceinline__ uint32_t pkbf16(float a, float b) {
    uint32_t ua = __float_as_uint(a);
    uint32_t ub = __float_as_uint(b);
    return ((ua + 0x8000u) >> 16) | ((ub + 0x8000u) & 0xffff0000u);
}

__device__ __forceinline__ bf16x8 pack8(f32x4 lo, f32x4 hi) {
    u32x4 u;
    u.x = pkbf16(lo[0], lo[1]);
    u.y = pkbf16(lo[2], lo[3]);
    u.z = pkbf16(hi[0], hi[1]);
    u.w = pkbf16(hi[2], hi[3]);
    return __builtin_bit_cast(bf16x8, u);
}

__global__ __launch_bounds__(256, 4) void ECGTokenizer_53420803228140_kernel(
    const float* __restrict__ ecg, const float* __restrict__ W,
    const float* __restrict__ b, float* __restrict__ out)
{
    // W fragments in LDS, fragment-major: slice (c*4+s) * 64 lanes * 16B.
    // Lane reads chunk [slice][lane] -> contiguous 1KB per wave read,
    // conflict-free.
    __shared__ short wlds[1024 * 8];   // 16 KiB

    const int lane = threadIdx.x & 63;
    const int wid  = threadIdx.x >> 6;
    const int l16  = lane & 15;   // ecg row within group / D col
    const int lg   = lane >> 4;   // k-subgroup (0..3)
    const int gwave = blockIdx.x * WPB + wid;  // 0..4095
    int rg = gwave * ITERS;                    // 3 consecutive row-groups

    // ---- first A row-group loads issued immediately (HBM, long latency) ----
    const float* arow = ecg + (size_t)rg * (16 * BEAT_LEN)
                      + (size_t)l16 * BEAT_LEN + 8 * lg;
    f32x4 a0[4], a1[4];
    #pragma unroll
    for (int s = 0; s < 4; ++s) {
        a0[s] = *(const f32x4*)(arow + 32*s);
        a1[s] = *(const f32x4*)(arow + 32*s + 4);
    }

    // ---- stage W (32 KB fp32 -> 16 KB bf16) into LDS, fragment order ----
    // chunk ch: slice = ch>>6 (= c*4+s), ln = ch&63; holds
    // W[16c + (ln&15)][32s + 8*(ln>>4) + e], e=0..7, packed bf16.
    for (int ch = threadIdx.x; ch < 1024; ch += 256) {
        const int slice = ch >> 6, ln = ch & 63;
        const int c = slice >> 2, s = slice & 3;
        const int sl16 = ln & 15, slg = ln >> 4;
        const float* wp = W + (16*c + sl16)*BEAT_LEN + 32*s + 8*slg;
        f32x4 w0 = *(const f32x4*)(wp);
        f32x4 w1 = *(const f32x4*)(wp + 4);
        *(bf16x8*)&wlds[ch * 8] = pack8(w0, w1);
    }
    __syncthreads();

    // bias: lane's 4 acc entries are d = 16c + 4*lg + {0..3} -> contiguous
    f32x4 bvv[4];
    #pragma unroll
    for (int c = 0; c < 4; ++c) bvv[c] = *(const f32x4*)(b + 16*c + 4*lg);

    #pragma unroll
    for (int it = 0; it < ITERS; ++it) {
        // pack current A (waits on its loads)
        bf16x8 af[4];
        #pragma unroll
        for (int s = 0; s < 4; ++s) af[s] = pack8(a0[s], a1[s]);

        // prefetch next row-group's A before compute/stores
        if (it + 1 < ITERS) {
            const float* anext = ecg + (size_t)(rg + 1) * (16 * BEAT_LEN)
                               + (size_t)l16 * BEAT_LEN + 8 * lg;
            #pragma unroll
            for (int s = 0; s < 4; ++s) {
                a0[s] = *(const f32x4*)(anext + 32*s);
                a1[s] = *(const f32x4*)(anext + 32*s + 4);
            }
        }

        f32x4 acc[4];
        #pragma unroll
        for (int c = 0; c < 4; ++c) acc[c] = bvv[c];

        #pragma unroll
        for (int s = 0; s < 4; ++s) {
            #pragma unroll
            for (int c = 0; c < 4; ++c) {
                bf16x8 wf = *(const bf16x8*)&wlds[((c*4 + s)*64 + lane) * 8];
                acc[c] = __builtin_amdgcn_mfma_f32_16x16x32_bf16(
                             wf, af[s], acc[c], 0, 0, 0);
            }
        }

        // D: row (W dim) = 4*lg + reg, col (m dim) = l16
        // lane stores X[rg*16 + l16][16c + 4lg .. +3] -> dwordx4, nontemporal
        float* orow = out + ((size_t)rg * 16 + l16) * TOKEN_DIM + 4*lg;
        #pragma unroll
        for (int c = 0; c < 4; ++c) {
            __builtin_nontemporal_store(acc[c], (f32x4*)(orow + 16*c));
        }
        ++rg;
    }

    // beat_intervals [128,128] = 128.0f, appended after X
    const int gtid = blockIdx.x * blockDim.x + threadIdx.x;
    if (gtid < N_BATCH * N_BEATS) {
        out[(size_t)M_ROWS * TOKEN_DIM + gtid] = 128.0f;
    }
}

extern "C" void kernel_launch(void* const* d_in, const int* in_sizes, int n_in,
                              void* d_out, int out_size, void* d_ws, size_t ws_size,
                              hipStream_t stream) {
    const float* ecg = (const float*)d_in[0];
    const float* W   = (const float*)d_in[1];
    const float* b   = (const float*)d_in[2];
    float* out       = (float*)d_out;
    hipLaunchKernelGGL(ECGTokenizer_53420803228140_kernel,
                       dim3(NBLOCKS), dim3(256), 0, stream,
                       ecg, W, b, out);
}